// Round 1
// baseline (317.377 us; speedup 1.0000x reference)
//
#include <hip/hip_runtime.h>

// out[t, j] = W[j, x[t]] + b[j]
//   x : [8*2048] int32        (in_sizes[0] = 16384)
//   W : [1024, 50257] float32 (row-major)
//   b : [1024] float32
//   out: [16384, 1024] float32
//
// One block per token. 256 threads * 4 j's = 1024 outputs per block.
// Output written as float4 (coalesced). W reads are column-gathers
// (stride 201KB) -- uncoalesced by nature, served by L2/L3 (W = 206MB
// fits in the 256MB Infinity Cache).

#define VOCAB 50257
#define DIM   1024

__global__ __launch_bounds__(256) void index2input_gather(
    const int* __restrict__ x,
    const float* __restrict__ W,
    const float* __restrict__ bias,
    float* __restrict__ out)
{
    const int token = blockIdx.x;
    const int v = x[token];              // wave-uniform -> scalar load
    const int j0 = threadIdx.x * 4;

    // 4 strided reads from column v of W
    float4 r;
    r.x = W[(size_t)(j0 + 0) * VOCAB + v];
    r.y = W[(size_t)(j0 + 1) * VOCAB + v];
    r.z = W[(size_t)(j0 + 2) * VOCAB + v];
    r.w = W[(size_t)(j0 + 3) * VOCAB + v];

    const float4 bb = *reinterpret_cast<const float4*>(bias + j0);
    r.x += bb.x; r.y += bb.y; r.z += bb.z; r.w += bb.w;

    *reinterpret_cast<float4*>(out + (size_t)token * DIM + j0) = r;
}

extern "C" void kernel_launch(void* const* d_in, const int* in_sizes, int n_in,
                              void* d_out, int out_size, void* d_ws, size_t ws_size,
                              hipStream_t stream) {
    const int*   x    = (const int*)d_in[0];
    const float* W    = (const float*)d_in[1];
    const float* bias = (const float*)d_in[2];
    float*       out  = (float*)d_out;

    const int n_tokens = in_sizes[0];   // 8 * 2048 = 16384

    index2input_gather<<<n_tokens, 256, 0, stream>>>(x, W, bias, out);
}

// Round 2
// 104.266 us; speedup vs baseline: 3.0439x; 3.0439x over previous
//
#include <hip/hip_runtime.h>

// out[t, j] = W[j, x[t]] + b[j]
//   x : [16384] int32, W : [1024, 50257] f32 row-major, b : [1024] f32
//   out: [16384, 1024] f32
//
// Round 1 showed FETCH = 1.05 GB = 16.8M loads x 64B: zero line reuse on the
// W column-gather. ~5.2 tokens share each 64B line (16 vocab entries), but
// they were scattered in time and across 8 non-coherent XCD L2s.
//
// Fix: counting-sort tokens by line-group (v>>4), then process the sorted
// order with an XCD-chunked block mapping so same-line tokens run close in
// time on the SAME XCD's L2. Expected FETCH ~= compulsory 205 MB.

#define VOCAB 50257
#define DIM   1024
#define NBUCK ((VOCAB + 15) >> 4)     // 3142 line-groups
#define NXCD  8

// ---------- sort pipeline (counting sort by v>>4) ----------

__global__ void zero_counts_kernel(int* __restrict__ counts, int n) {
    int i = blockIdx.x * blockDim.x + threadIdx.x;
    if (i < n) counts[i] = 0;
}

__global__ void hist_kernel(const int* __restrict__ x, int n, int* __restrict__ counts) {
    int i = blockIdx.x * blockDim.x + threadIdx.x;
    if (i < n) atomicAdd(&counts[x[i] >> 4], 1);
}

// single block, 256 threads: exclusive prefix sum over NBUCK counters
__global__ __launch_bounds__(256) void scan_kernel(const int* __restrict__ counts,
                                                   int* __restrict__ offs) {
    const int CHUNK = (NBUCK + 255) / 256;   // 13
    __shared__ int lds[256];
    const int tid = threadIdx.x;
    const int base = tid * CHUNK;
    int local[CHUNK];
    int s = 0;
#pragma unroll
    for (int k = 0; k < CHUNK; ++k) {
        int idx = base + k;
        int c = (idx < NBUCK) ? counts[idx] : 0;
        local[k] = s;
        s += c;
    }
    lds[tid] = s;
    __syncthreads();
    if (tid == 0) {
        int run = 0;
        for (int i = 0; i < 256; ++i) { int c = lds[i]; lds[i] = run; run += c; }
    }
    __syncthreads();
    const int boff = lds[tid];
#pragma unroll
    for (int k = 0; k < CHUNK; ++k) {
        int idx = base + k;
        if (idx < NBUCK) offs[idx] = boff + local[k];
    }
}

// offs is consumed as running cursors (recomputed every call -> deterministic output)
__global__ void scatter_kernel(const int* __restrict__ x, int n,
                               int* __restrict__ offs, int* __restrict__ order) {
    int i = blockIdx.x * blockDim.x + threadIdx.x;
    if (i < n) {
        int pos = atomicAdd(&offs[x[i] >> 4], 1);
        order[pos] = i;
    }
}

// ---------- gather ----------

// Bijective XCD chunking (m204 form): hw block bid -> logical sorted index so
// that XCD k (= bid % 8, round-robin dispatch) owns one contiguous sorted range.
__global__ __launch_bounds__(256) void gather_sorted_kernel(
    const int* __restrict__ x,
    const float* __restrict__ W,
    const float* __restrict__ bias,
    const int* __restrict__ order,
    float* __restrict__ out,
    int n, int q, int r)   // q = n/8, r = n%8
{
    const int bid = blockIdx.x;
    const int xcd = bid & (NXCD - 1);
    const int idx = bid >> 3;
    const int chunk_base = (xcd < r) ? xcd * (q + 1) : r * (q + 1) + (xcd - r) * q;
    const int logical = chunk_base + idx;

    const int t = order[logical];        // block-uniform -> scalar load
    const int v = x[t];
    const int j0 = threadIdx.x * 4;

    float4 rr;
    rr.x = W[(size_t)(j0 + 0) * VOCAB + v];
    rr.y = W[(size_t)(j0 + 1) * VOCAB + v];
    rr.z = W[(size_t)(j0 + 2) * VOCAB + v];
    rr.w = W[(size_t)(j0 + 3) * VOCAB + v];

    const float4 bb = *reinterpret_cast<const float4*>(bias + j0);
    rr.x += bb.x; rr.y += bb.y; rr.z += bb.z; rr.w += bb.w;

    *reinterpret_cast<float4*>(out + (size_t)t * DIM + j0) = rr;
}

// fallback (round-1 kernel) if workspace is too small for the sort
__global__ __launch_bounds__(256) void gather_direct_kernel(
    const int* __restrict__ x,
    const float* __restrict__ W,
    const float* __restrict__ bias,
    float* __restrict__ out)
{
    const int t = blockIdx.x;
    const int v = x[t];
    const int j0 = threadIdx.x * 4;
    float4 rr;
    rr.x = W[(size_t)(j0 + 0) * VOCAB + v];
    rr.y = W[(size_t)(j0 + 1) * VOCAB + v];
    rr.z = W[(size_t)(j0 + 2) * VOCAB + v];
    rr.w = W[(size_t)(j0 + 3) * VOCAB + v];
    const float4 bb = *reinterpret_cast<const float4*>(bias + j0);
    rr.x += bb.x; rr.y += bb.y; rr.z += bb.z; rr.w += bb.w;
    *reinterpret_cast<float4*>(out + (size_t)t * DIM + j0) = rr;
}

extern "C" void kernel_launch(void* const* d_in, const int* in_sizes, int n_in,
                              void* d_out, int out_size, void* d_ws, size_t ws_size,
                              hipStream_t stream) {
    const int*   x    = (const int*)d_in[0];
    const float* W    = (const float*)d_in[1];
    const float* bias = (const float*)d_in[2];
    float*       out  = (float*)d_out;

    const int n = in_sizes[0];           // 16384 tokens

    const size_t need = (size_t)(2 * NBUCK + n) * sizeof(int);
    if (ws_size < need) {
        gather_direct_kernel<<<n, 256, 0, stream>>>(x, W, bias, out);
        return;
    }

    int* counts = (int*)d_ws;            // [NBUCK]
    int* offs   = counts + NBUCK;        // [NBUCK]
    int* order  = offs + NBUCK;          // [n]

    const int tb = 256;
    zero_counts_kernel<<<(NBUCK + tb - 1) / tb, tb, 0, stream>>>(counts, NBUCK);
    hist_kernel<<<(n + tb - 1) / tb, tb, 0, stream>>>(x, n, counts);
    scan_kernel<<<1, tb, 0, stream>>>(counts, offs);
    scatter_kernel<<<(n + tb - 1) / tb, tb, 0, stream>>>(x, n, offs, order);

    const int q = n / NXCD, r = n % NXCD;
    gather_sorted_kernel<<<n, 256, 0, stream>>>(x, W, bias, order, out, n, q, r);
}